// Round 16
// baseline (919.310 us; speedup 1.0000x reference)
//
#include <hip/hip_runtime.h>

typedef __attribute__((ext_vector_type(8))) short bf16x8;
typedef __attribute__((ext_vector_type(4))) float f32x4;
typedef __attribute__((ext_vector_type(4))) int i32x4;
typedef unsigned int u32;

#define B_SZ   64
#define IMGSZ  12288            // 3*64*64
#define ENC_H  800
#define DEC_H  1600
#define NZ     100
#define NENC   6400             // 4*ENC_H*2 (mu ++ lv)
#define KHH    832              // 13 chunks
#define KDEC   1728             // 27 chunks
#define GSZ    (B_SZ*NENC)
#define SLICES 5                // loop gpart slices: 3 int8 + 1 W_C + 1 hh
#define G0SL   8

// centered int8: delta = sigmoid(c)-0.5 in [-.5,.5], d_q = round(delta*254)
// w_q = round(w*1008); -delta.W_B = SCALE_I8*sum(d_q*w_q); -0.5*colsum exact
#define WQMUL    1008.0f
#define SCALE_I8 (-1.0f/(254.0f*1008.0f))

__device__ __forceinline__ unsigned short f2bf(float f){
  unsigned u = __float_as_uint(f);
  u += 0x7fffu + ((u >> 16) & 1u);
  return (unsigned short)(u >> 16);
}
__device__ __forceinline__ float bf2f(unsigned short h){
  return __uint_as_float(((unsigned)h) << 16);
}
__device__ __forceinline__ float sigf(float x){ return 1.f/(1.f + __expf(-x)); }
__device__ __forceinline__ ushort4 cv4(float4 v){
  ushort4 o; o.x=f2bf(v.x); o.y=f2bf(v.y); o.z=f2bf(v.z); o.w=f2bf(v.w); return o;
}
__device__ __forceinline__ unsigned q4(float4 v){
  int a = __float2int_rn(fminf(fmaxf(v.x*WQMUL, -127.f), 127.f));
  int b = __float2int_rn(fminf(fmaxf(v.y*WQMUL, -127.f), 127.f));
  int c = __float2int_rn(fminf(fmaxf(v.z*WQMUL, -127.f), 127.f));
  int d = __float2int_rn(fminf(fmaxf(v.w*WQMUL, -127.f), 127.f));
  return (a&255) | ((b&255)<<8) | ((c&255)<<16) | ((d&255)<<24);
}

__device__ __forceinline__ void gllb(const void* g, void* l){
  __builtin_amdgcn_global_load_lds((const __attribute__((address_space(1))) u32*)g,
                                   (__attribute__((address_space(3))) u32*)l, 16, 0, 0);
}

// ---- bf16 LDS-staged GEMM, 3-buffer counted-vmcnt ----
__device__ __forceinline__ void gemm_lds3(const unsigned short* __restrict__ A, int lda, int k0,
                                          const unsigned short* __restrict__ Bpk, size_t bchunk0,
                                          int nchb, unsigned short (*sm)[4096], f32x4 acc[4])
{
  const int tid = threadIdx.x;
  const int lane = tid & 63, w = tid >> 6;
  const int l15 = lane & 15, lg = lane >> 4;
  const int l8 = lane >> 3, l7 = lane & 7;

  const unsigned short* gA0 = A + (size_t)(w*16 + l8)*lda + k0 + (l7 ^ l8)*8;
  const unsigned short* gA1 = gA0 + (size_t)8*lda;
  const unsigned short* gB0 = Bpk + bchunk0*4096 + w*1024 + lane*8;

#pragma unroll
  for (int m = 0; m < 4; ++m) acc[m] = (f32x4){0.f,0.f,0.f,0.f};

  gllb(gA0, &sm[0][(w*2+0)*512]);
  gllb(gA1, &sm[0][(w*2+1)*512]);
  gllb(gB0,       &sm[1][w*1024]);
  gllb(gB0 + 512, &sm[1][w*1024 + 512]);
  if (1 < nchb){
    gllb(gA0 + 64, &sm[2][(w*2+0)*512]);
    gllb(gA1 + 64, &sm[2][(w*2+1)*512]);
    gllb(gB0 + 4096,       &sm[3][w*1024]);
    gllb(gB0 + 4096 + 512, &sm[3][w*1024 + 512]);
  }

  int cur = 0, nxt = 2;
  for (int c = 0; c < nchb; ++c){
    if (c + 1 < nchb) { asm volatile("s_waitcnt vmcnt(4)" ::: "memory"); }
    else              { asm volatile("s_waitcnt vmcnt(0)" ::: "memory"); }
    asm volatile("s_barrier" ::: "memory");
    const unsigned short* sa = sm[cur*2];
    const unsigned short* sb = sm[cur*2 + 1];
#pragma unroll
    for (int h = 0; h < 2; ++h){
      const int su8 = ((h*4 + lg) ^ (l15 & 7)) * 8;
      bf16x8 bfr = *(const bf16x8*)&sb[(w*16 + l15)*64 + su8];
#pragma unroll
      for (int m = 0; m < 4; ++m){
        bf16x8 afr = *(const bf16x8*)&sa[(m*16 + l15)*64 + su8];
        acc[m] = __builtin_amdgcn_mfma_f32_16x16x32_bf16(afr, bfr, acc[m], 0,0,0);
      }
    }
    if (c + 2 < nchb){
      const size_t ao = (size_t)(c+2)*64, bo = (size_t)(c+2)*4096;
      gllb(gA0 + ao, &sm[nxt*2][(w*2+0)*512]);
      gllb(gA1 + ao, &sm[nxt*2][(w*2+1)*512]);
      gllb(gB0 + bo,       &sm[nxt*2+1][w*1024]);
      gllb(gB0 + bo + 512, &sm[nxt*2+1][w*1024 + 512]);
    }
    cur = (cur==2) ? 0 : cur+1;
    nxt = (nxt==2) ? 0 : nxt+1;
  }
}

// ---- int8 LDS-staged GEMM, 5-buffer distance-4 counted-vmcnt ----
// Per chunk per wave: 2 gllb (A 1KB + B 1KB). Graded tail ladder ensures
// chunk c's loads landed: outstanding = 2*(chunks in flight beyond c).
// Buffer overwrite safe: iteration-c barrier orders all waves past
// compute(c-1) before any wave stages into buf((c+4)%5) == buf(c-1).
__device__ __forceinline__ void gemm_i8(const signed char* __restrict__ A, int lda, int k0,
                                        const signed char* __restrict__ Bpk, size_t bch0,
                                        int nch, unsigned char* sm, i32x4 acc[4])
{
  const int tid = threadIdx.x;
  const int lane = tid & 63, w = tid >> 6;
  const int l15 = lane & 15, lg = lane >> 4;

  const int rp = lane >> 3, un = lane & 7;
  const int swz = un ^ (rp & 7);
  const int rloc = rp*2 + ((swz >> 2) & 1);
  const int uA = swz & 3;
  const signed char* gA = A + (size_t)(w*16 + rloc)*lda + k0 + uA*16;
  const signed char* gB = Bpk + bch0*4096 + w*1024 + lane*16;

#pragma unroll
  for (int m = 0; m < 4; ++m) acc[m] = (i32x4){0,0,0,0};

#define I8_STAGE(c_, b_) {                                                    \
    gllb(gA + (size_t)(c_)*64,   sm + (size_t)(b_)*8192 + w*1024 + lane*16);  \
    gllb(gB + (size_t)(c_)*4096, sm + (size_t)(b_)*8192 + 4096 + w*1024 + lane*16); }

  I8_STAGE(0, 0);
  if (1 < nch) I8_STAGE(1, 1);
  if (2 < nch) I8_STAGE(2, 2);
  if (3 < nch) I8_STAGE(3, 3);

  const int rB = w*16 + l15;
  const int offB = 4096 + (rB>>1)*128 + (((((rB&1)<<2) + lg) ^ ((rB>>1)&7))*16);

  int cur = 0;
  for (int c = 0; c < nch; ++c){
    if      (c + 3 < nch) { asm volatile("s_waitcnt vmcnt(6)" ::: "memory"); }
    else if (c + 2 < nch) { asm volatile("s_waitcnt vmcnt(4)" ::: "memory"); }
    else if (c + 1 < nch) { asm volatile("s_waitcnt vmcnt(2)" ::: "memory"); }
    else                  { asm volatile("s_waitcnt vmcnt(0)" ::: "memory"); }
    asm volatile("s_barrier" ::: "memory");
    const unsigned char* s = sm + (size_t)cur*8192;
    i32x4 bfr = *(const i32x4*)(s + offB);
#pragma unroll
    for (int m = 0; m < 4; ++m){
      int rA = m*16 + l15;
      i32x4 afr = *(const i32x4*)(s + (rA>>1)*128 + (((((rA&1)<<2) + lg) ^ ((rA>>1)&7))*16));
      acc[m] = __builtin_amdgcn_mfma_i32_16x16x64_i8(afr, bfr, acc[m], 0, 0, 0);
    }
    if (c + 4 < nch) I8_STAGE(c + 4, (c + 4) % 5);
    cur = (cur == 4) ? 0 : cur + 1;
  }
#undef I8_STAGE
}

__device__ __forceinline__ void store_out1(f32x4 acc[4], float* __restrict__ Out,
                                           int ldo, int col0){
  const int lane = threadIdx.x & 63, w = threadIdx.x >> 6;
  const int l15 = lane & 15, lg = lane >> 4;
  int col = col0 + w*16 + l15;
#pragma unroll
  for (int m = 0; m < 4; ++m)
#pragma unroll
    for (int j = 0; j < 4; ++j)
      Out[(size_t)(m*16 + lg*4 + j)*ldo + col] = acc[m][j];
}

__device__ __forceinline__ void store_i8(i32x4 acc[4], float* __restrict__ Out,
                                         int ldo, int col0){
  const int lane = threadIdx.x & 63, w = threadIdx.x >> 6;
  const int l15 = lane & 15, lg = lane >> 4;
  int col = col0 + w*16 + l15;
#pragma unroll
  for (int m = 0; m < 4; ++m)
#pragma unroll
    for (int j = 0; j < 4; ++j)
      Out[(size_t)(m*16 + lg*4 + j)*ldo + col] = SCALE_I8 * (float)acc[m][j];
}

// ---- merged setup mega-kernel (r13 verbatim) ----
#define R_ENCM 19200
#define R_WHC  21700
#define R_WHH  23000
#define R_WDEC 25700
#define R_WWR  30500
#define R_MISC 31425
#define M_FC   40000u
#define M_XBF  236608u

__global__ __launch_bounds__(256) void k_pack_all(
    const float* __restrict__ Wihmu, const float* __restrict__ Wihlv,
    const float* __restrict__ Whhmu, const float* __restrict__ Whhlv,
    const float* __restrict__ Whhdec, const float* __restrict__ Wihdec,
    const float* __restrict__ Wwrite, const float* __restrict__ Wmufc,
    const float* __restrict__ Wlvfc, const float* __restrict__ x,
    unsigned short* __restrict__ wab, unsigned char* __restrict__ wi8,
    float* __restrict__ csPart, unsigned short* __restrict__ whc,
    unsigned short* __restrict__ whh, unsigned short* __restrict__ wdec,
    unsigned short* __restrict__ wwr, unsigned short* __restrict__ wfcmu,
    unsigned short* __restrict__ wfclv, unsigned short* __restrict__ xbf)
{
  int bid = blockIdx.x;
  if (bid < R_ENCM){
    __shared__ float cs[256];
    int ch = bid % 192, cb = bid / 192;
    int t = threadIdx.x;
    int r = t >> 2, seg = t & 3;
    int col = cb*64 + r;
    const float4* src = (col < 3200) ? ((const float4*)Wihmu + (size_t)col*6544)
                                     : ((const float4*)Wihlv + (size_t)(col-3200)*6544);
    int k4b = ch*16 + seg*4;
    float4 va[4], vb[4];
#pragma unroll
    for (int i = 0; i < 4; ++i){ va[i] = src[k4b+i]; vb[i] = src[3072 + k4b + i]; }

    ushort4* wabT = (ushort4*)wab + ((size_t)cb*192 + ch)*1024;
#pragma unroll
    for (int d = 0; d < 2; ++d){
      int u16 = seg*2 + d;
      int su = u16 ^ (r & 7);
      float4 s0, s1;
      s0.x=va[2*d].x+vb[2*d].x;   s0.y=va[2*d].y+vb[2*d].y;
      s0.z=va[2*d].z+vb[2*d].z;   s0.w=va[2*d].w+vb[2*d].w;
      s1.x=va[2*d+1].x+vb[2*d+1].x; s1.y=va[2*d+1].y+vb[2*d+1].y;
      s1.z=va[2*d+1].z+vb[2*d+1].z; s1.w=va[2*d+1].w+vb[2*d+1].w;
      wabT[r*16 + su*2 + 0] = cv4(s0);
      wabT[r*16 + su*2 + 1] = cv4(s1);
    }

    unsigned char* wi8T = wi8 + ((size_t)cb*192 + ch)*4096;
    int unit = (((r&1)<<2) + seg) ^ ((r>>1) & 7);
    uint4 pk;
    pk.x = q4(vb[0]); pk.y = q4(vb[1]); pk.z = q4(vb[2]); pk.w = q4(vb[3]);
    *(uint4*)(wi8T + (r>>1)*128 + unit*16) = pk;

    float s = 0.f;
#pragma unroll
    for (int i = 0; i < 4; ++i) s += vb[i].x + vb[i].y + vb[i].z + vb[i].w;
    cs[t] = s;
    __syncthreads();
    if (seg == 0)
      csPart[((size_t)col)*192 + ch] = cs[t] + cs[t+1] + cs[t+2] + cs[t+3];
  }
  else if (bid < R_WHC){
    int i = bid - R_ENCM;
    int ch = i % 25, cb = i / 25;
    ushort4* whcT = (ushort4*)whc + ((size_t)cb*25 + ch)*1024;
#pragma unroll
    for (int qv = 0; qv < 4; ++qv){
      int ou = qv*256 + threadIdx.x;
      int r = ou >> 4, qq = ou & 15;
      int su = qq >> 1, half = qq & 1;
      int uu = su ^ (r & 7);
      int k4 = ch*16 + uu*2 + half;
      int col = cb*64 + r;
      const float4* src = (col < 3200) ? ((const float4*)Wihmu + (size_t)col*6544)
                                       : ((const float4*)Wihlv + (size_t)(col-3200)*6544);
      whcT[ou] = cv4(src[6144 + k4]);
    }
  }
  else if (bid < R_WHH){
    int i = bid - R_WHC;
    int ch = i % 13, cb = i / 13;
    ushort4* whhT = (ushort4*)whh + ((size_t)cb*13 + ch)*1024;
#pragma unroll
    for (int qv = 0; qv < 4; ++qv){
      int ou = qv*256 + threadIdx.x;
      int r = ou >> 4, qq = ou & 15;
      int su = qq >> 1, half = qq & 1;
      int uu = su ^ (r & 7);
      int k4 = ch*16 + uu*2 + half;
      int col = cb*64 + r;
      float4 v = {0.f,0.f,0.f,0.f};
      if (k4 < 200)
        v = (col < 3200) ? ((const float4*)Whhmu)[(size_t)col*200 + k4]
                         : ((const float4*)Whhlv)[(size_t)(col-3200)*200 + k4];
      whhT[ou] = cv4(v);
    }
  }
  else if (bid < R_WDEC){
    int i = bid - R_WHH;
    int ch = i % 27, cb = i / 27;
    ushort4* wdecT = (ushort4*)wdec + ((size_t)cb*27 + ch)*1024;
#pragma unroll
    for (int qv = 0; qv < 4; ++qv){
      int ou = qv*256 + threadIdx.x;
      int r = ou >> 4, qq = ou & 15;
      int su = qq >> 1, half = qq & 1;
      int uu = su ^ (r & 7);
      int k4 = ch*16 + uu*2 + half;
      int pr = cb*64 + r;
      unsigned j = pr >> 2, g = pr & 3, srow = g*1600u + j;
      float4 v = {0.f,0.f,0.f,0.f};
      if (k4 < 400)      v = ((const float4*)Whhdec)[(size_t)srow*400 + k4];
      else if (k4 < 425) v = ((const float4*)Wihdec)[(size_t)srow*25 + (k4-400)];
      wdecT[ou] = cv4(v);
    }
  }
  else if (bid < R_WWR){
    int i = bid - R_WDEC;
    int ch = i % 25, cb = i / 25;
    ushort4* wwrT = (ushort4*)wwr + ((size_t)cb*25 + ch)*1024;
#pragma unroll
    for (int qv = 0; qv < 4; ++qv){
      int ou = qv*256 + threadIdx.x;
      int r = ou >> 4, qq = ou & 15;
      int su = qq >> 1, half = qq & 1;
      int uu = su ^ (r & 7);
      int k4 = ch*16 + uu*2 + half;
      int p = cb*64 + r;
      wwrT[ou] = cv4(((const float4*)Wwrite)[(size_t)p*400 + k4]);
    }
  }
  else {
    unsigned i = (unsigned)(bid - R_WWR)*256u + threadIdx.x;
    if (i >= M_XBF) return;
    if (i < M_FC){
      if (i < 20000u) ((ushort4*)wfcmu)[i] = cv4(((const float4*)Wmufc)[i]);
      else            ((ushort4*)wfclv)[i-20000u] = cv4(((const float4*)Wlvfc)[i-20000u]);
    } else {
      unsigned j = i - M_FC;
      ((ushort4*)xbf)[j] = cv4(((const float4*)x)[j]);
    }
  }
}

// colsum reduce: 6400 cols x 192 partials
__global__ __launch_bounds__(256) void k_csred(const float* __restrict__ csPart,
                                               float* __restrict__ colsum){
  unsigned col = blockIdx.x*blockDim.x + threadIdx.x;
  if (col >= NENC) return;
  const float* p = csPart + (size_t)col*192;
  float s = 0.f;
#pragma unroll 8
  for (int ch = 0; ch < 192; ++ch) s += p[ch];
  colsum[col] = s;
}

// ---- GEMM kernels ----

__global__ __launch_bounds__(256) void k_g0(const unsigned short* __restrict__ xbf,
                                            const unsigned short* __restrict__ wab,
                                            float* __restrict__ gpart){
  __shared__ __align__(16) unsigned short smem[6][4096];
  int bid = blockIdx.x;                 // 800
  int s = bid/100, cb = bid - s*100;
  f32x4 acc[4];
  gemm_lds3(xbf, IMGSZ, s*1536, wab, (size_t)cb*192 + s*24, 24, smem, acc);
  store_out1(acc, gpart + (size_t)s*GSZ, NENC, cb*64);
}

__global__ __launch_bounds__(256) void k_g0red(const float* __restrict__ gpart,
                                               float* __restrict__ g0){
  unsigned i = blockIdx.x*blockDim.x + threadIdx.x;
  if (i >= GSZ) return;
  float s = 0.f;
#pragma unroll
  for (int p = 0; p < G0SL; ++p) s += gpart[(size_t)p*GSZ + i];
  g0[i] = s;
}

// 300 int8 (3 slices x 100 cb) + 100 W_C + 100 hh + 100 dec_h = 600 blocks
__global__ __launch_bounds__(256) void k_enc(const signed char* __restrict__ ui8,
                                             const signed char* __restrict__ wi8,
                                             const unsigned short* __restrict__ uhd,
                                             const unsigned short* __restrict__ whc,
                                             const unsigned short* __restrict__ hmup,
                                             const unsigned short* __restrict__ hlvp,
                                             const unsigned short* __restrict__ whh,
                                             const unsigned short* __restrict__ wdec,
                                             float* __restrict__ gpart,
                                             float* __restrict__ gdecH){
  __shared__ __align__(16) unsigned char smem[49152];
  int bid = blockIdx.x;
  if (bid < 300){
    int s = bid/100, cb = bid - s*100;
    int ch0 = s*64;                            // 3 x 64 = 192 chunks exactly
    i32x4 acc[4];
    gemm_i8(ui8, IMGSZ, ch0*64, wi8, (size_t)cb*192 + ch0, 64, smem, acc);
    store_i8(acc, gpart + (size_t)s*GSZ, NENC, cb*64);
  } else if (bid < 400){
    int cb = bid - 300;
    f32x4 acc[4];
    gemm_lds3(uhd, DEC_H, 0, whc, (size_t)cb*25, 25,
              (unsigned short (*)[4096])smem, acc);
    store_out1(acc, gpart + (size_t)3*GSZ, NENC, cb*64);
  } else if (bid < 500){
    int cb = bid - 400;
    const unsigned short* A = (cb < 50) ? hmup : hlvp;
    f32x4 acc[4];
    gemm_lds3(A, KHH, 0, whh, (size_t)cb*13, 13,
              (unsigned short (*)[4096])smem, acc);
    store_out1(acc, gpart + (size_t)4*GSZ, NENC, cb*64);
  } else {
    int cb = bid - 500;                        // dec_h: K=1600 (chunks 0..24)
    f32x4 acc[4];
    gemm_lds3(uhd, DEC_H, 0, wdec, (size_t)cb*27, 25,
              (unsigned short (*)[4096])smem, acc);
    store_out1(acc, gdecH, NENC, cb*64);
  }
}

// merged enc LSTM cell + mu/lv fc + z: 64 blocks, 512 thr
__global__ __launch_bounds__(512) void k_cell(const float* __restrict__ g0,
                                              const float* __restrict__ gpart,
                                              const float* __restrict__ colsum,
                                              const float* __restrict__ bmu,
                                              const float* __restrict__ blv,
                                              float* __restrict__ cmu,
                                              float* __restrict__ clv,
                                              unsigned short* __restrict__ hmup,
                                              unsigned short* __restrict__ hlvp,
                                              const unsigned short* __restrict__ wfcmu,
                                              const unsigned short* __restrict__ wfclv,
                                              const float* __restrict__ bmufc,
                                              const float* __restrict__ blvfc,
                                              const float* __restrict__ noise_t,
                                              float* __restrict__ outMu,
                                              float* __restrict__ outLv,
                                              unsigned short* __restrict__ uz){
  __shared__ float hsh[1600];
  __shared__ float red[512];
  int b = blockIdx.x, tid = threadIdx.x;

  for (int uidx = tid; uidx < 1600; uidx += 512){
    int which = uidx >= 800;
    int j = uidx - which*800;
    const float* bias = which ? blv : bmu;
    int cbase = which*3200 + j;
    size_t rowoff = (size_t)b*NENC + cbase;
    float a0 = bias[j]       - 0.5f*colsum[cbase];
    float a1 = bias[800+j]   - 0.5f*colsum[cbase+800];
    float a2 = bias[1600+j]  - 0.5f*colsum[cbase+1600];
    float a3 = bias[2400+j]  - 0.5f*colsum[cbase+2400];
    const float* q = g0 + rowoff;
    a0 += q[0]; a1 += q[800]; a2 += q[1600]; a3 += q[2400];
#pragma unroll
    for (int s = 0; s < SLICES; ++s){
      const float* p = gpart + (size_t)s*GSZ + rowoff;
      a0 += p[0]; a1 += p[800]; a2 += p[1600]; a3 += p[2400];
    }
    float* C = which ? clv : cmu;
    float cold = C[(size_t)b*ENC_H + j];
    float cn = sigf(a1)*cold + sigf(a0)*tanhf(a2);
    float h  = sigf(a3)*tanhf(cn);
    C[(size_t)b*ENC_H + j] = cn;
    (which ? hlvp : hmup)[(size_t)b*KHH + j] = f2bf(h);
    hsh[uidx] = h;
  }
  __syncthreads();

  if (tid < 400){
    int o = tid >> 1, half = tid & 1;
    int ismu = o < 100;
    int row = ismu ? o : o - 100;
    const unsigned short* wrow = (ismu ? wfcmu : wfclv) + (size_t)row*ENC_H + half*400;
    const float* hbase = hsh + (ismu ? 0 : 800) + half*400;
    float s = 0.f;
#pragma unroll 4
    for (int k = 0; k < 100; ++k){
      ushort4 wv = ((const ushort4*)wrow)[k];
      s += bf2f(wv.x)*hbase[k*4]   + bf2f(wv.y)*hbase[k*4+1]
         + bf2f(wv.z)*hbase[k*4+2] + bf2f(wv.w)*hbase[k*4+3];
    }
    red[tid] = s;
  }
  __syncthreads();
  if (tid < 200){
    int o = tid; int ismu = o < 100; int row = ismu ? o : o - 100;
    float s = red[2*o] + red[2*o+1] + (ismu ? bmufc[row] : blvfc[row]);
    s = fmaxf(s, 0.f);
    if (ismu) outMu[(size_t)b*NZ + row] = s;
    else      outLv[(size_t)b*NZ + row] = s;
    hsh[o] = s;
  }
  __syncthreads();
  if (tid < 100){
    float mu = hsh[tid], lv = hsh[100 + tid];
    float z = noise_t[(size_t)b*NZ + tid]*__expf(0.5f*lv) + mu;
    uz[(size_t)b*128 + tid] = f2bf(z);
  }
}

// dec z-part GEMM (K=128, wdec chunks 25,26) + gdecH add + LSTM cell epilogue
__global__ __launch_bounds__(256) void k_decz(const unsigned short* __restrict__ uz,
                                              const unsigned short* __restrict__ wdec,
                                              const float* __restrict__ gdecH,
                                              const float* __restrict__ bdec,
                                              float* __restrict__ cdec,
                                              unsigned short* __restrict__ uhd){
  __shared__ __align__(16) unsigned short smem[6][4096];
  int bid = blockIdx.x;                       // 100 blocks
  f32x4 acc[4];
  gemm_lds3(uz, 128, 0, wdec, (size_t)bid*27 + 25, 2, smem, acc);
  const int lane = threadIdx.x & 63;
  const int wave = threadIdx.x >> 6;
  const int l15 = lane & 15, lg = lane >> 4;
  {
    int col = bid*64 + wave*16 + l15;
#pragma unroll
    for (int m = 0; m < 4; ++m)
#pragma unroll
      for (int j = 0; j < 4; ++j)
        acc[m][j] += gdecH[(size_t)(m*16 + lg*4 + j)*NENC + col];
  }
  __syncthreads();
  float* lds = (float*)&smem[0][0];
#pragma unroll
  for (int m = 0; m < 4; ++m)
#pragma unroll
    for (int j = 0; j < 4; ++j)
      lds[(m*16 + lg*4 + j)*65 + wave*16 + l15] = acc[m][j];
  __syncthreads();
#pragma unroll
  for (int p = 0; p < 4; ++p){
    int idx = threadIdx.x + p*256;
    int b = idx & 63, jj = idx >> 6;
    const float* g4 = &lds[b*65 + jj*4];
    int j = bid*16 + jj;
    float gi = g4[0] + bdec[j];
    float gf = g4[1] + bdec[DEC_H + j];
    float gg = g4[2] + bdec[2*DEC_H + j];
    float go = g4[3] + bdec[3*DEC_H + j];
    float cold = cdec[(size_t)b*DEC_H + j];
    float cn = sigf(gf)*cold + sigf(gi)*tanhf(gg);
    float h  = sigf(go)*tanhf(cn);
    cdec[(size_t)b*DEC_H + j] = cn;
    uhd[(size_t)b*DEC_H + j] = f2bf(h);
  }
}

// write GEMM fused: canvas += h@Wwr^T + b ; ui8 = round((sigmoid(cv)-0.5)*254)
__global__ __launch_bounds__(256) void k_write(const unsigned short* __restrict__ uhd,
                                               const unsigned short* __restrict__ wwr,
                                               const float* __restrict__ bwr,
                                               float* __restrict__ canvas,
                                               signed char* __restrict__ ui8){
  __shared__ __align__(16) unsigned short smem[6][4096];
  f32x4 acc[4];
  gemm_lds3(uhd, DEC_H, 0, wwr, (size_t)blockIdx.x*25, 25, smem, acc);
  const int lane = threadIdx.x & 63;
  const int wave = threadIdx.x >> 6;
  const int l15 = lane & 15, lg = lane >> 4;
  int col = blockIdx.x*64 + wave*16 + l15;
#pragma unroll
  for (int m = 0; m < 4; ++m){
#pragma unroll
    for (int j = 0; j < 4; ++j){
      int row = m*16 + lg*4 + j;
      float cv = canvas[(size_t)row*IMGSZ + col] + acc[m][j] + bwr[col];
      canvas[(size_t)row*IMGSZ + col] = cv;
      ui8[(size_t)row*IMGSZ + col] =
        (signed char)__float2int_rn((sigf(cv) - 0.5f)*254.f);
    }
  }
}

__global__ __launch_bounds__(256) void k_final(const float* __restrict__ canvas,
                                               float* __restrict__ out){
  unsigned i = blockIdx.x*blockDim.x + threadIdx.x;
  if (i < (unsigned)(B_SZ*IMGSZ)) out[i] = sigf(canvas[i]);
}

// ---- workspace layout ----
constexpr size_t SZ_WAB    = (size_t)NENC*IMGSZ*2;
constexpr size_t SZ_WI8    = (size_t)NENC*IMGSZ;
constexpr size_t SZ_WHC    = (size_t)NENC*DEC_H*2;
constexpr size_t SZ_WHH    = (size_t)NENC*KHH*2;
constexpr size_t SZ_WDEC   = (size_t)NENC*KDEC*2;
constexpr size_t SZ_WWR    = (size_t)IMGSZ*DEC_H*2;
constexpr size_t SZ_WFC    = (size_t)NZ*ENC_H*2;
constexpr size_t SZ_XBF    = (size_t)B_SZ*IMGSZ*2;
constexpr size_t SZ_CSPART = (size_t)NENC*192*4;
constexpr size_t SZ_CSUM   = (size_t)NENC*4;
constexpr size_t SZ_G0     = (size_t)GSZ*4;
constexpr size_t SZ_GPART  = (size_t)G0SL*GSZ*4;
constexpr size_t SZ_GDECH  = (size_t)B_SZ*NENC*4;
constexpr size_t SZ_CANVAS = (size_t)B_SZ*IMGSZ*4;
constexpr size_t SZ_CMU    = (size_t)B_SZ*ENC_H*4;
constexpr size_t SZ_CDEC   = (size_t)B_SZ*DEC_H*4;
constexpr size_t SZ_HP     = (size_t)B_SZ*KHH*2;
constexpr size_t SZ_UHD    = (size_t)B_SZ*DEC_H*2;
constexpr size_t SZ_UZ     = (size_t)B_SZ*128*2;
constexpr size_t SZ_UI8    = (size_t)B_SZ*IMGSZ;

constexpr size_t OFF_WAB    = 0;
constexpr size_t OFF_WI8    = OFF_WAB    + SZ_WAB;
constexpr size_t OFF_WHC    = OFF_WI8    + SZ_WI8;
constexpr size_t OFF_WHH    = OFF_WHC    + SZ_WHC;
constexpr size_t OFF_WDEC   = OFF_WHH    + SZ_WHH;
constexpr size_t OFF_WWR    = OFF_WDEC   + SZ_WDEC;
constexpr size_t OFF_WFCMU  = OFF_WWR    + SZ_WWR;
constexpr size_t OFF_WFCLV  = OFF_WFCMU  + SZ_WFC;
constexpr size_t OFF_XBF    = OFF_WFCLV  + SZ_WFC;
constexpr size_t OFF_CSPART = OFF_XBF    + SZ_XBF;
constexpr size_t OFF_CSUM   = OFF_CSPART + SZ_CSPART;
constexpr size_t OFF_G0     = OFF_CSUM   + SZ_CSUM;
constexpr size_t OFF_GPART  = OFF_G0     + SZ_G0;
constexpr size_t OFF_GDECH  = OFF_GPART  + SZ_GPART;
constexpr size_t OFF_CANVAS = OFF_GDECH  + SZ_GDECH;   // zero-init span start
constexpr size_t OFF_CMU    = OFF_CANVAS + SZ_CANVAS;
constexpr size_t OFF_CLV    = OFF_CMU    + SZ_CMU;
constexpr size_t OFF_CDEC   = OFF_CLV    + SZ_CMU;
constexpr size_t OFF_HMUP   = OFF_CDEC   + SZ_CDEC;
constexpr size_t OFF_HLVP   = OFF_HMUP   + SZ_HP;
constexpr size_t OFF_UHD    = OFF_HLVP   + SZ_HP;
constexpr size_t OFF_UZ     = OFF_UHD    + SZ_UHD;
constexpr size_t OFF_UI8    = OFF_UZ     + SZ_UZ;      // delta=0 -> zero init
constexpr size_t OFF_END    = OFF_UI8    + SZ_UI8;

extern "C" void kernel_launch(void* const* d_in, const int* in_sizes, int n_in,
                              void* d_out, int out_size, void* d_ws, size_t ws_size,
                              hipStream_t stream) {
  const float* x      = (const float*)d_in[0];
  const float* noise  = (const float*)d_in[1];
  const float* Wihmu  = (const float*)d_in[2];
  const float* Whhmu  = (const float*)d_in[3];
  const float* bmu    = (const float*)d_in[4];
  const float* Wihlv  = (const float*)d_in[5];
  const float* Whhlv  = (const float*)d_in[6];
  const float* blv    = (const float*)d_in[7];
  const float* Wmufc  = (const float*)d_in[8];
  const float* bmufc  = (const float*)d_in[9];
  const float* Wlvfc  = (const float*)d_in[10];
  const float* blvfc  = (const float*)d_in[11];
  const float* Wihdec = (const float*)d_in[12];
  const float* Whhdec = (const float*)d_in[13];
  const float* bdec   = (const float*)d_in[14];
  const float* Wwrite = (const float*)d_in[15];
  const float* bwrite = (const float*)d_in[16];
  int T = in_sizes[1] / (B_SZ*NZ);

  if (ws_size < OFF_END) return;

  char* ws = (char*)d_ws;
  unsigned short* wab   = (unsigned short*)(ws + OFF_WAB);
  unsigned char*  wi8   = (unsigned char*)(ws + OFF_WI8);
  unsigned short* whc   = (unsigned short*)(ws + OFF_WHC);
  unsigned short* whh   = (unsigned short*)(ws + OFF_WHH);
  unsigned short* wdec  = (unsigned short*)(ws + OFF_WDEC);
  unsigned short* wwr   = (unsigned short*)(ws + OFF_WWR);
  unsigned short* wfcmu = (unsigned short*)(ws + OFF_WFCMU);
  unsigned short* wfclv = (unsigned short*)(ws + OFF_WFCLV);
  unsigned short* xbf   = (unsigned short*)(ws + OFF_XBF);
  float* csPart = (float*)(ws + OFF_CSPART);
  float* colsum = (float*)(ws + OFF_CSUM);
  float* g0     = (float*)(ws + OFF_G0);
  float* gpart  = (float*)(ws + OFF_GPART);
  float* gdecH  = (float*)(ws + OFF_GDECH);
  float* canvas = (float*)(ws + OFF_CANVAS);
  float* cmu    = (float*)(ws + OFF_CMU);
  float* clv    = (float*)(ws + OFF_CLV);
  float* cdec   = (float*)(ws + OFF_CDEC);
  unsigned short* hmup = (unsigned short*)(ws + OFF_HMUP);
  unsigned short* hlvp = (unsigned short*)(ws + OFF_HLVP);
  unsigned short* uhd  = (unsigned short*)(ws + OFF_UHD);
  unsigned short* uz   = (unsigned short*)(ws + OFF_UZ);
  signed char* ui8 = (signed char*)(ws + OFF_UI8);

  float* out = (float*)d_out;
  float* outMu = out + (size_t)B_SZ*IMGSZ;
  float* outLv = outMu + (size_t)T*B_SZ*NZ;

  dim3 blk(256);

  k_pack_all<<<R_MISC, blk, 0, stream>>>(Wihmu, Wihlv, Whhmu, Whhlv,
                                         Whhdec, Wihdec, Wwrite, Wmufc, Wlvfc, x,
                                         wab, wi8, csPart, whc, whh, wdec, wwr,
                                         wfcmu, wfclv, xbf);
  k_csred<<<(NENC + 255)/256, blk, 0, stream>>>(csPart, colsum);
  hipMemsetAsync(ws + OFF_CANVAS, 0, OFF_END - OFF_CANVAS, stream);

  k_g0<<<800, blk, 0, stream>>>(xbf, wab, gpart);
  k_g0red<<<GSZ/256, blk, 0, stream>>>(gpart, g0);

  for (int t = 0; t < T; ++t){
    k_enc<<<600, blk, 0, stream>>>(ui8, (const signed char*)wi8, uhd, whc,
                                   hmup, hlvp, whh, wdec, gpart, gdecH);
    k_cell<<<B_SZ, 512, 0, stream>>>(g0, gpart, colsum, bmu, blv, cmu, clv,
                                     hmup, hlvp, wfcmu, wfclv, bmufc, blvfc,
                                     noise + (size_t)t*B_SZ*NZ,
                                     outMu + (size_t)t*B_SZ*NZ,
                                     outLv + (size_t)t*B_SZ*NZ, uz);
    k_decz<<<100, blk, 0, stream>>>(uz, wdec, gdecH, bdec, cdec, uhd);
    k_write<<<IMGSZ/64, blk, 0, stream>>>(uhd, wwr, bwrite, canvas, ui8);
  }

  k_final<<<(B_SZ*IMGSZ)/256, blk, 0, stream>>>(canvas, out);
}

// Round 17
// 903.975 us; speedup vs baseline: 1.0170x; 1.0170x over previous
//
#include <hip/hip_runtime.h>

typedef __attribute__((ext_vector_type(8))) short bf16x8;
typedef __attribute__((ext_vector_type(4))) float f32x4;
typedef __attribute__((ext_vector_type(4))) int i32x4;
typedef unsigned int u32;

#define B_SZ   64
#define IMGSZ  12288            // 3*64*64
#define ENC_H  800
#define DEC_H  1600
#define NZ     100
#define NENC   6400             // 4*ENC_H*2 (mu ++ lv)
#define KHH    832              // 13 chunks
#define KDEC   1728             // 27 chunks
#define GSZ    (B_SZ*NENC)
#define SLICES 5                // loop gpart slices: 3 int8 + 1 W_C + 1 hh
#define G0SL   8

// centered int8: delta = sigmoid(c)-0.5 in [-.5,.5], d_q = round(delta*254)
// w_q = round(w*1008); -delta.W_B = SCALE_I8*sum(d_q*w_q); -0.5*colsum exact
#define WQMUL    1008.0f
#define SCALE_I8 (-1.0f/(254.0f*1008.0f))

__device__ __forceinline__ unsigned short f2bf(float f){
  unsigned u = __float_as_uint(f);
  u += 0x7fffu + ((u >> 16) & 1u);
  return (unsigned short)(u >> 16);
}
__device__ __forceinline__ float bf2f(unsigned short h){
  return __uint_as_float(((unsigned)h) << 16);
}
__device__ __forceinline__ float sigf(float x){ return 1.f/(1.f + __expf(-x)); }
__device__ __forceinline__ ushort4 cv4(float4 v){
  ushort4 o; o.x=f2bf(v.x); o.y=f2bf(v.y); o.z=f2bf(v.z); o.w=f2bf(v.w); return o;
}
__device__ __forceinline__ unsigned q4(float4 v){
  int a = __float2int_rn(fminf(fmaxf(v.x*WQMUL, -127.f), 127.f));
  int b = __float2int_rn(fminf(fmaxf(v.y*WQMUL, -127.f), 127.f));
  int c = __float2int_rn(fminf(fmaxf(v.z*WQMUL, -127.f), 127.f));
  int d = __float2int_rn(fminf(fmaxf(v.w*WQMUL, -127.f), 127.f));
  return (a&255) | ((b&255)<<8) | ((c&255)<<16) | ((d&255)<<24);
}

__device__ __forceinline__ void gllb(const void* g, void* l){
  __builtin_amdgcn_global_load_lds((const __attribute__((address_space(1))) u32*)g,
                                   (__attribute__((address_space(3))) u32*)l, 16, 0, 0);
}

// ---- bf16 LDS-staged GEMM, 3-buffer counted-vmcnt ----
__device__ __forceinline__ void gemm_lds3(const unsigned short* __restrict__ A, int lda, int k0,
                                          const unsigned short* __restrict__ Bpk, size_t bchunk0,
                                          int nchb, unsigned short (*sm)[4096], f32x4 acc[4])
{
  const int tid = threadIdx.x;
  const int lane = tid & 63, w = tid >> 6;
  const int l15 = lane & 15, lg = lane >> 4;
  const int l8 = lane >> 3, l7 = lane & 7;

  const unsigned short* gA0 = A + (size_t)(w*16 + l8)*lda + k0 + (l7 ^ l8)*8;
  const unsigned short* gA1 = gA0 + (size_t)8*lda;
  const unsigned short* gB0 = Bpk + bchunk0*4096 + w*1024 + lane*8;

#pragma unroll
  for (int m = 0; m < 4; ++m) acc[m] = (f32x4){0.f,0.f,0.f,0.f};

  gllb(gA0, &sm[0][(w*2+0)*512]);
  gllb(gA1, &sm[0][(w*2+1)*512]);
  gllb(gB0,       &sm[1][w*1024]);
  gllb(gB0 + 512, &sm[1][w*1024 + 512]);
  if (1 < nchb){
    gllb(gA0 + 64, &sm[2][(w*2+0)*512]);
    gllb(gA1 + 64, &sm[2][(w*2+1)*512]);
    gllb(gB0 + 4096,       &sm[3][w*1024]);
    gllb(gB0 + 4096 + 512, &sm[3][w*1024 + 512]);
  }

  int cur = 0, nxt = 2;
  for (int c = 0; c < nchb; ++c){
    if (c + 1 < nchb) { asm volatile("s_waitcnt vmcnt(4)" ::: "memory"); }
    else              { asm volatile("s_waitcnt vmcnt(0)" ::: "memory"); }
    asm volatile("s_barrier" ::: "memory");
    const unsigned short* sa = sm[cur*2];
    const unsigned short* sb = sm[cur*2 + 1];
#pragma unroll
    for (int h = 0; h < 2; ++h){
      const int su8 = ((h*4 + lg) ^ (l15 & 7)) * 8;
      bf16x8 bfr = *(const bf16x8*)&sb[(w*16 + l15)*64 + su8];
#pragma unroll
      for (int m = 0; m < 4; ++m){
        bf16x8 afr = *(const bf16x8*)&sa[(m*16 + l15)*64 + su8];
        acc[m] = __builtin_amdgcn_mfma_f32_16x16x32_bf16(afr, bfr, acc[m], 0,0,0);
      }
    }
    if (c + 2 < nchb){
      const size_t ao = (size_t)(c+2)*64, bo = (size_t)(c+2)*4096;
      gllb(gA0 + ao, &sm[nxt*2][(w*2+0)*512]);
      gllb(gA1 + ao, &sm[nxt*2][(w*2+1)*512]);
      gllb(gB0 + bo,       &sm[nxt*2+1][w*1024]);
      gllb(gB0 + bo + 512, &sm[nxt*2+1][w*1024 + 512]);
    }
    cur = (cur==2) ? 0 : cur+1;
    nxt = (nxt==2) ? 0 : nxt+1;
  }
}

// ---- int8 LDS-staged GEMM, 3-buffer counted-vmcnt (r14 form) ----
__device__ __forceinline__ void gemm_i8(const signed char* __restrict__ A, int lda, int k0,
                                        const signed char* __restrict__ Bpk, size_t bch0,
                                        int nch, unsigned char* sm, i32x4 acc[4])
{
  const int tid = threadIdx.x;
  const int lane = tid & 63, w = tid >> 6;
  const int l15 = lane & 15, lg = lane >> 4;

  const int rp = lane >> 3, un = lane & 7;
  const int swz = un ^ (rp & 7);
  const int rloc = rp*2 + ((swz >> 2) & 1);
  const int uA = swz & 3;
  const signed char* gA = A + (size_t)(w*16 + rloc)*lda + k0 + uA*16;
  const signed char* gB = Bpk + bch0*4096 + w*1024 + lane*16;

#pragma unroll
  for (int m = 0; m < 4; ++m) acc[m] = (i32x4){0,0,0,0};

  {
    gllb(gA, sm + 0*8192 + w*1024 + lane*16);
    gllb(gB, sm + 0*8192 + 4096 + w*1024 + lane*16);
    if (1 < nch){
      gllb(gA + 64,   sm + 1*8192 + w*1024 + lane*16);
      gllb(gB + 4096, sm + 1*8192 + 4096 + w*1024 + lane*16);
    }
  }

  const int rB = w*16 + l15;
  const int offB = 4096 + (rB>>1)*128 + (((((rB&1)<<2) + lg) ^ ((rB>>1)&7))*16);

  int cur = 0, nxt = 2;
  for (int c = 0; c < nch; ++c){
    if (c + 1 < nch) { asm volatile("s_waitcnt vmcnt(2)" ::: "memory"); }
    else             { asm volatile("s_waitcnt vmcnt(0)" ::: "memory"); }
    asm volatile("s_barrier" ::: "memory");
    const unsigned char* s = sm + cur*8192;
    i32x4 bfr = *(const i32x4*)(s + offB);
#pragma unroll
    for (int m = 0; m < 4; ++m){
      int rA = m*16 + l15;
      i32x4 afr = *(const i32x4*)(s + (rA>>1)*128 + (((((rA&1)<<2) + lg) ^ ((rA>>1)&7))*16));
      acc[m] = __builtin_amdgcn_mfma_i32_16x16x64_i8(afr, bfr, acc[m], 0, 0, 0);
    }
    if (c + 2 < nch){
      gllb(gA + (size_t)(c+2)*64,   sm + nxt*8192 + w*1024 + lane*16);
      gllb(gB + (size_t)(c+2)*4096, sm + nxt*8192 + 4096 + w*1024 + lane*16);
    }
    cur = (cur==2) ? 0 : cur+1;
    nxt = (nxt==2) ? 0 : nxt+1;
  }
}

__device__ __forceinline__ void store_out1(f32x4 acc[4], float* __restrict__ Out,
                                           int ldo, int col0){
  const int lane = threadIdx.x & 63, w = threadIdx.x >> 6;
  const int l15 = lane & 15, lg = lane >> 4;
  int col = col0 + w*16 + l15;
#pragma unroll
  for (int m = 0; m < 4; ++m)
#pragma unroll
    for (int j = 0; j < 4; ++j)
      Out[(size_t)(m*16 + lg*4 + j)*ldo + col] = acc[m][j];
}

__device__ __forceinline__ void store_i8(i32x4 acc[4], float* __restrict__ Out,
                                         int ldo, int col0){
  const int lane = threadIdx.x & 63, w = threadIdx.x >> 6;
  const int l15 = lane & 15, lg = lane >> 4;
  int col = col0 + w*16 + l15;
#pragma unroll
  for (int m = 0; m < 4; ++m)
#pragma unroll
    for (int j = 0; j < 4; ++j)
      Out[(size_t)(m*16 + lg*4 + j)*ldo + col] = SCALE_I8 * (float)acc[m][j];
}

// ---- merged setup mega-kernel ----
#define R_ENCM 19200
#define R_WHC  21700
#define R_WHH  23000
#define R_WDEC 25700
#define R_WWR  30500
#define R_MISC 31425
#define M_FC   40000u
#define M_XBF  236608u

__global__ __launch_bounds__(256) void k_pack_all(
    const float* __restrict__ Wihmu, const float* __restrict__ Wihlv,
    const float* __restrict__ Whhmu, const float* __restrict__ Whhlv,
    const float* __restrict__ Whhdec, const float* __restrict__ Wihdec,
    const float* __restrict__ Wwrite, const float* __restrict__ Wmufc,
    const float* __restrict__ Wlvfc, const float* __restrict__ x,
    unsigned short* __restrict__ wab, unsigned char* __restrict__ wi8,
    float* __restrict__ csPart, unsigned short* __restrict__ whc,
    unsigned short* __restrict__ whh, unsigned short* __restrict__ wdec,
    unsigned short* __restrict__ wwr, unsigned short* __restrict__ wfcmu,
    unsigned short* __restrict__ wfclv, unsigned short* __restrict__ xbf)
{
  int bid = blockIdx.x;
  if (bid < R_ENCM){
    __shared__ float cs[256];
    int ch = bid % 192, cb = bid / 192;
    int t = threadIdx.x;
    int r = t >> 2, seg = t & 3;
    int col = cb*64 + r;
    const float4* src = (col < 3200) ? ((const float4*)Wihmu + (size_t)col*6544)
                                     : ((const float4*)Wihlv + (size_t)(col-3200)*6544);
    int k4b = ch*16 + seg*4;
    float4 va[4], vb[4];
#pragma unroll
    for (int i = 0; i < 4; ++i){ va[i] = src[k4b+i]; vb[i] = src[3072 + k4b + i]; }

    ushort4* wabT = (ushort4*)wab + ((size_t)cb*192 + ch)*1024;
#pragma unroll
    for (int d = 0; d < 2; ++d){
      int u16 = seg*2 + d;
      int su = u16 ^ (r & 7);
      float4 s0, s1;
      s0.x=va[2*d].x+vb[2*d].x;   s0.y=va[2*d].y+vb[2*d].y;
      s0.z=va[2*d].z+vb[2*d].z;   s0.w=va[2*d].w+vb[2*d].w;
      s1.x=va[2*d+1].x+vb[2*d+1].x; s1.y=va[2*d+1].y+vb[2*d+1].y;
      s1.z=va[2*d+1].z+vb[2*d+1].z; s1.w=va[2*d+1].w+vb[2*d+1].w;
      wabT[r*16 + su*2 + 0] = cv4(s0);
      wabT[r*16 + su*2 + 1] = cv4(s1);
    }

    unsigned char* wi8T = wi8 + ((size_t)cb*192 + ch)*4096;
    int unit = (((r&1)<<2) + seg) ^ ((r>>1) & 7);
    uint4 pk;
    pk.x = q4(vb[0]); pk.y = q4(vb[1]); pk.z = q4(vb[2]); pk.w = q4(vb[3]);
    *(uint4*)(wi8T + (r>>1)*128 + unit*16) = pk;

    float s = 0.f;
#pragma unroll
    for (int i = 0; i < 4; ++i) s += vb[i].x + vb[i].y + vb[i].z + vb[i].w;
    cs[t] = s;
    __syncthreads();
    if (seg == 0)
      csPart[((size_t)col)*192 + ch] = cs[t] + cs[t+1] + cs[t+2] + cs[t+3];
  }
  else if (bid < R_WHC){
    int i = bid - R_ENCM;
    int ch = i % 25, cb = i / 25;
    ushort4* whcT = (ushort4*)whc + ((size_t)cb*25 + ch)*1024;
#pragma unroll
    for (int qv = 0; qv < 4; ++qv){
      int ou = qv*256 + threadIdx.x;
      int r = ou >> 4, qq = ou & 15;
      int su = qq >> 1, half = qq & 1;
      int uu = su ^ (r & 7);
      int k4 = ch*16 + uu*2 + half;
      int col = cb*64 + r;
      const float4* src = (col < 3200) ? ((const float4*)Wihmu + (size_t)col*6544)
                                       : ((const float4*)Wihlv + (size_t)(col-3200)*6544);
      whcT[ou] = cv4(src[6144 + k4]);
    }
  }
  else if (bid < R_WHH){
    int i = bid - R_WHC;
    int ch = i % 13, cb = i / 13;
    ushort4* whhT = (ushort4*)whh + ((size_t)cb*13 + ch)*1024;
#pragma unroll
    for (int qv = 0; qv < 4; ++qv){
      int ou = qv*256 + threadIdx.x;
      int r = ou >> 4, qq = ou & 15;
      int su = qq >> 1, half = qq & 1;
      int uu = su ^ (r & 7);
      int k4 = ch*16 + uu*2 + half;
      int col = cb*64 + r;
      float4 v = {0.f,0.f,0.f,0.f};
      if (k4 < 200)
        v = (col < 3200) ? ((const float4*)Whhmu)[(size_t)col*200 + k4]
                         : ((const float4*)Whhlv)[(size_t)(col-3200)*200 + k4];
      whhT[ou] = cv4(v);
    }
  }
  else if (bid < R_WDEC){
    int i = bid - R_WHH;
    int ch = i % 27, cb = i / 27;
    ushort4* wdecT = (ushort4*)wdec + ((size_t)cb*27 + ch)*1024;
#pragma unroll
    for (int qv = 0; qv < 4; ++qv){
      int ou = qv*256 + threadIdx.x;
      int r = ou >> 4, qq = ou & 15;
      int su = qq >> 1, half = qq & 1;
      int uu = su ^ (r & 7);
      int k4 = ch*16 + uu*2 + half;
      int pr = cb*64 + r;
      unsigned j = pr >> 2, g = pr & 3, srow = g*1600u + j;
      float4 v = {0.f,0.f,0.f,0.f};
      if (k4 < 400)      v = ((const float4*)Whhdec)[(size_t)srow*400 + k4];
      else if (k4 < 425) v = ((const float4*)Wihdec)[(size_t)srow*25 + (k4-400)];
      wdecT[ou] = cv4(v);
    }
  }
  else if (bid < R_WWR){
    int i = bid - R_WDEC;
    int ch = i % 25, cb = i / 25;
    ushort4* wwrT = (ushort4*)wwr + ((size_t)cb*25 + ch)*1024;
#pragma unroll
    for (int qv = 0; qv < 4; ++qv){
      int ou = qv*256 + threadIdx.x;
      int r = ou >> 4, qq = ou & 15;
      int su = qq >> 1, half = qq & 1;
      int uu = su ^ (r & 7);
      int k4 = ch*16 + uu*2 + half;
      int p = cb*64 + r;
      wwrT[ou] = cv4(((const float4*)Wwrite)[(size_t)p*400 + k4]);
    }
  }
  else {
    unsigned i = (unsigned)(bid - R_WWR)*256u + threadIdx.x;
    if (i >= M_XBF) return;
    if (i < M_FC){
      if (i < 20000u) ((ushort4*)wfcmu)[i] = cv4(((const float4*)Wmufc)[i]);
      else            ((ushort4*)wfclv)[i-20000u] = cv4(((const float4*)Wlvfc)[i-20000u]);
    } else {
      unsigned j = i - M_FC;
      ((ushort4*)xbf)[j] = cv4(((const float4*)x)[j]);
    }
  }
}

// colsum reduce: 6400 cols x 192 partials
__global__ __launch_bounds__(256) void k_csred(const float* __restrict__ csPart,
                                               float* __restrict__ colsum){
  unsigned col = blockIdx.x*blockDim.x + threadIdx.x;
  if (col >= NENC) return;
  const float* p = csPart + (size_t)col*192;
  float s = 0.f;
#pragma unroll 8
  for (int ch = 0; ch < 192; ++ch) s += p[ch];
  colsum[col] = s;
}

// ---- GEMM kernels ----

__global__ __launch_bounds__(256) void k_g0(const unsigned short* __restrict__ xbf,
                                            const unsigned short* __restrict__ wab,
                                            float* __restrict__ gpart){
  __shared__ __align__(16) unsigned short smem[6][4096];
  int bid = blockIdx.x;                 // 800
  int s = bid/100, cb = bid - s*100;
  f32x4 acc[4];
  gemm_lds3(xbf, IMGSZ, s*1536, wab, (size_t)cb*192 + s*24, 24, smem, acc);
  store_out1(acc, gpart + (size_t)s*GSZ, NENC, cb*64);
}

__global__ __launch_bounds__(256) void k_g0red(const float* __restrict__ gpart,
                                               float* __restrict__ g0){
  unsigned i = blockIdx.x*blockDim.x + threadIdx.x;
  if (i >= GSZ) return;
  float s = 0.f;
#pragma unroll
  for (int p = 0; p < G0SL; ++p) s += gpart[(size_t)p*GSZ + i];
  g0[i] = s;
}

// 300 int8 (3 slices x 100 cb) + 100 W_C + 100 hh + 100 dec_h = 600 blocks
__global__ __launch_bounds__(256) void k_enc(const signed char* __restrict__ ui8,
                                             const signed char* __restrict__ wi8,
                                             const unsigned short* __restrict__ uhd,
                                             const unsigned short* __restrict__ whc,
                                             const unsigned short* __restrict__ hmup,
                                             const unsigned short* __restrict__ hlvp,
                                             const unsigned short* __restrict__ whh,
                                             const unsigned short* __restrict__ wdec,
                                             float* __restrict__ gpart,
                                             float* __restrict__ gdecH){
  __shared__ __align__(16) unsigned char smem[49152];
  int bid = blockIdx.x;
  if (bid < 300){
    int s = bid/100, cb = bid - s*100;
    int ch0 = s*64;                            // 3 x 64 = 192 chunks exactly
    i32x4 acc[4];
    gemm_i8(ui8, IMGSZ, ch0*64, wi8, (size_t)cb*192 + ch0, 64, smem, acc);
    store_i8(acc, gpart + (size_t)s*GSZ, NENC, cb*64);
  } else if (bid < 400){
    int cb = bid - 300;
    f32x4 acc[4];
    gemm_lds3(uhd, DEC_H, 0, whc, (size_t)cb*25, 25,
              (unsigned short (*)[4096])smem, acc);
    store_out1(acc, gpart + (size_t)3*GSZ, NENC, cb*64);
  } else if (bid < 500){
    int cb = bid - 400;
    const unsigned short* A = (cb < 50) ? hmup : hlvp;
    f32x4 acc[4];
    gemm_lds3(A, KHH, 0, whh, (size_t)cb*13, 13,
              (unsigned short (*)[4096])smem, acc);
    store_out1(acc, gpart + (size_t)4*GSZ, NENC, cb*64);
  } else {
    int cb = bid - 500;                        // dec_h: K=1600 (chunks 0..24)
    f32x4 acc[4];
    gemm_lds3(uhd, DEC_H, 0, wdec, (size_t)cb*27, 25,
              (unsigned short (*)[4096])smem, acc);
    store_out1(acc, gdecH, NENC, cb*64);
  }
}

// merged enc LSTM cell + mu/lv fc + z: 64 blocks, 512 thr
__global__ __launch_bounds__(512) void k_cell(const float* __restrict__ g0,
                                              const float* __restrict__ gpart,
                                              const float* __restrict__ colsum,
                                              const float* __restrict__ bmu,
                                              const float* __restrict__ blv,
                                              float* __restrict__ cmu,
                                              float* __restrict__ clv,
                                              unsigned short* __restrict__ hmup,
                                              unsigned short* __restrict__ hlvp,
                                              const unsigned short* __restrict__ wfcmu,
                                              const unsigned short* __restrict__ wfclv,
                                              const float* __restrict__ bmufc,
                                              const float* __restrict__ blvfc,
                                              const float* __restrict__ noise_t,
                                              float* __restrict__ outMu,
                                              float* __restrict__ outLv,
                                              unsigned short* __restrict__ uz){
  __shared__ float hsh[1600];
  __shared__ float red[512];
  int b = blockIdx.x, tid = threadIdx.x;

  for (int uidx = tid; uidx < 1600; uidx += 512){
    int which = uidx >= 800;
    int j = uidx - which*800;
    const float* bias = which ? blv : bmu;
    int cbase = which*3200 + j;
    size_t rowoff = (size_t)b*NENC + cbase;
    float a0 = bias[j]       - 0.5f*colsum[cbase];
    float a1 = bias[800+j]   - 0.5f*colsum[cbase+800];
    float a2 = bias[1600+j]  - 0.5f*colsum[cbase+1600];
    float a3 = bias[2400+j]  - 0.5f*colsum[cbase+2400];
    const float* q = g0 + rowoff;
    a0 += q[0]; a1 += q[800]; a2 += q[1600]; a3 += q[2400];
#pragma unroll
    for (int s = 0; s < SLICES; ++s){
      const float* p = gpart + (size_t)s*GSZ + rowoff;
      a0 += p[0]; a1 += p[800]; a2 += p[1600]; a3 += p[2400];
    }
    float* C = which ? clv : cmu;
    float cold = C[(size_t)b*ENC_H + j];
    float cn = sigf(a1)*cold + sigf(a0)*tanhf(a2);
    float h  = sigf(a3)*tanhf(cn);
    C[(size_t)b*ENC_H + j] = cn;
    (which ? hlvp : hmup)[(size_t)b*KHH + j] = f2bf(h);
    hsh[uidx] = h;
  }
  __syncthreads();

  if (tid < 400){
    int o = tid >> 1, half = tid & 1;
    int ismu = o < 100;
    int row = ismu ? o : o - 100;
    const unsigned short* wrow = (ismu ? wfcmu : wfclv) + (size_t)row*ENC_H + half*400;
    const float* hbase = hsh + (ismu ? 0 : 800) + half*400;
    float s = 0.f;
#pragma unroll 4
    for (int k = 0; k < 100; ++k){
      ushort4 wv = ((const ushort4*)wrow)[k];
      s += bf2f(wv.x)*hbase[k*4]   + bf2f(wv.y)*hbase[k*4+1]
         + bf2f(wv.z)*hbase[k*4+2] + bf2f(wv.w)*hbase[k*4+3];
    }
    red[tid] = s;
  }
  __syncthreads();
  if (tid < 200){
    int o = tid; int ismu = o < 100; int row = ismu ? o : o - 100;
    float s = red[2*o] + red[2*o+1] + (ismu ? bmufc[row] : blvfc[row]);
    s = fmaxf(s, 0.f);
    if (ismu) outMu[(size_t)b*NZ + row] = s;
    else      outLv[(size_t)b*NZ + row] = s;
    hsh[o] = s;
  }
  __syncthreads();
  if (tid < 100){
    float mu = hsh[tid], lv = hsh[100 + tid];
    float z = noise_t[(size_t)b*NZ + tid]*__expf(0.5f*lv) + mu;
    uz[(size_t)b*128 + tid] = f2bf(z);
  }
}

// dec z-part GEMM (K=128, wdec chunks 25,26) + gdecH add + LSTM cell epilogue
__global__ __launch_bounds__(256) void k_decz(const unsigned short* __restrict__ uz,
                                              const unsigned short* __restrict__ wdec,
                                              const float* __restrict__ gdecH,
                                              const float* __restrict__ bdec,
                                              float* __restrict__ cdec,
                                              unsigned short* __restrict__ uhd){
  __shared__ __align__(16) unsigned short smem[6][4096];
  int bid = blockIdx.x;                       // 100 blocks
  f32x4 acc[4];
  gemm_lds3(uz, 128, 0, wdec, (size_t)bid*27 + 25, 2, smem, acc);
  const int lane = threadIdx.x & 63;
  const int wave = threadIdx.x >> 6;
  const int l15 = lane & 15, lg = lane >> 4;
  {
    int col = bid*64 + wave*16 + l15;
#pragma unroll
    for (int m = 0; m < 4; ++m)
#pragma unroll
      for (int j = 0; j < 4; ++j)
        acc[m][j] += gdecH[(size_t)(m*16 + lg*4 + j)*NENC + col];
  }
  __syncthreads();
  float* lds = (float*)&smem[0][0];
#pragma unroll
  for (int m = 0; m < 4; ++m)
#pragma unroll
    for (int j = 0; j < 4; ++j)
      lds[(m*16 + lg*4 + j)*65 + wave*16 + l15] = acc[m][j];
  __syncthreads();
#pragma unroll
  for (int p = 0; p < 4; ++p){
    int idx = threadIdx.x + p*256;
    int b = idx & 63, jj = idx >> 6;
    const float* g4 = &lds[b*65 + jj*4];
    int j = bid*16 + jj;
    float gi = g4[0] + bdec[j];
    float gf = g4[1] + bdec[DEC_H + j];
    float gg = g4[2] + bdec[2*DEC_H + j];
    float go = g4[3] + bdec[3*DEC_H + j];
    float cold = cdec[(size_t)b*DEC_H + j];
    float cn = sigf(gf)*cold + sigf(gi)*tanhf(gg);
    float h  = sigf(go)*tanhf(cn);
    cdec[(size_t)b*DEC_H + j] = cn;
    uhd[(size_t)b*DEC_H + j] = f2bf(h);
  }
}

// write GEMM fused: canvas += h@Wwr^T + b ; ui8 = round((sigmoid(cv)-0.5)*254)
__global__ __launch_bounds__(256) void k_write(const unsigned short* __restrict__ uhd,
                                               const unsigned short* __restrict__ wwr,
                                               const float* __restrict__ bwr,
                                               float* __restrict__ canvas,
                                               signed char* __restrict__ ui8){
  __shared__ __align__(16) unsigned short smem[6][4096];
  f32x4 acc[4];
  gemm_lds3(uhd, DEC_H, 0, wwr, (size_t)blockIdx.x*25, 25, smem, acc);
  const int lane = threadIdx.x & 63;
  const int wave = threadIdx.x >> 6;
  const int l15 = lane & 15, lg = lane >> 4;
  int col = blockIdx.x*64 + wave*16 + l15;
#pragma unroll
  for (int m = 0; m < 4; ++m){
#pragma unroll
    for (int j = 0; j < 4; ++j){
      int row = m*16 + lg*4 + j;
      float cv = canvas[(size_t)row*IMGSZ + col] + acc[m][j] + bwr[col];
      canvas[(size_t)row*IMGSZ + col] = cv;
      ui8[(size_t)row*IMGSZ + col] =
        (signed char)__float2int_rn((sigf(cv) - 0.5f)*254.f);
    }
  }
}

__global__ __launch_bounds__(256) void k_final(const float* __restrict__ canvas,
                                               float* __restrict__ out){
  unsigned i = blockIdx.x*blockDim.x + threadIdx.x;
  if (i < (unsigned)(B_SZ*IMGSZ)) out[i] = sigf(canvas[i]);
}

// ---- workspace layout ----
constexpr size_t SZ_WAB    = (size_t)NENC*IMGSZ*2;
constexpr size_t SZ_WI8    = (size_t)NENC*IMGSZ;
constexpr size_t SZ_WHC    = (size_t)NENC*DEC_H*2;
constexpr size_t SZ_WHH    = (size_t)NENC*KHH*2;
constexpr size_t SZ_WDEC   = (size_t)NENC*KDEC*2;
constexpr size_t SZ_WWR    = (size_t)IMGSZ*DEC_H*2;
constexpr size_t SZ_WFC    = (size_t)NZ*ENC_H*2;
constexpr size_t SZ_XBF    = (size_t)B_SZ*IMGSZ*2;
constexpr size_t SZ_CSPART = (size_t)NENC*192*4;
constexpr size_t SZ_CSUM   = (size_t)NENC*4;
constexpr size_t SZ_G0     = (size_t)GSZ*4;
constexpr size_t SZ_GPART  = (size_t)G0SL*GSZ*4;
constexpr size_t SZ_GDECH  = (size_t)B_SZ*NENC*4;
constexpr size_t SZ_CANVAS = (size_t)B_SZ*IMGSZ*4;
constexpr size_t SZ_CMU    = (size_t)B_SZ*ENC_H*4;
constexpr size_t SZ_CDEC   = (size_t)B_SZ*DEC_H*4;
constexpr size_t SZ_HP     = (size_t)B_SZ*KHH*2;
constexpr size_t SZ_UHD    = (size_t)B_SZ*DEC_H*2;
constexpr size_t SZ_UZ     = (size_t)B_SZ*128*2;
constexpr size_t SZ_UI8    = (size_t)B_SZ*IMGSZ;

constexpr size_t OFF_WAB    = 0;
constexpr size_t OFF_WI8    = OFF_WAB    + SZ_WAB;
constexpr size_t OFF_WHC    = OFF_WI8    + SZ_WI8;
constexpr size_t OFF_WHH    = OFF_WHC    + SZ_WHC;
constexpr size_t OFF_WDEC   = OFF_WHH    + SZ_WHH;
constexpr size_t OFF_WWR    = OFF_WDEC   + SZ_WDEC;
constexpr size_t OFF_WFCMU  = OFF_WWR    + SZ_WWR;
constexpr size_t OFF_WFCLV  = OFF_WFCMU  + SZ_WFC;
constexpr size_t OFF_XBF    = OFF_WFCLV  + SZ_WFC;
constexpr size_t OFF_CSPART = OFF_XBF    + SZ_XBF;
constexpr size_t OFF_CSUM   = OFF_CSPART + SZ_CSPART;
constexpr size_t OFF_G0     = OFF_CSUM   + SZ_CSUM;
constexpr size_t OFF_GPART  = OFF_G0     + SZ_G0;
constexpr size_t OFF_GDECH  = OFF_GPART  + SZ_GPART;
constexpr size_t OFF_CANVAS = OFF_GDECH  + SZ_GDECH;   // zero-init span start
constexpr size_t OFF_CMU    = OFF_CANVAS + SZ_CANVAS;
constexpr size_t OFF_CLV    = OFF_CMU    + SZ_CMU;
constexpr size_t OFF_CDEC   = OFF_CLV    + SZ_CMU;
constexpr size_t OFF_HMUP   = OFF_CDEC   + SZ_CDEC;
constexpr size_t OFF_HLVP   = OFF_HMUP   + SZ_HP;
constexpr size_t OFF_UHD    = OFF_HLVP   + SZ_HP;
constexpr size_t OFF_UZ     = OFF_UHD    + SZ_UHD;
constexpr size_t OFF_UI8    = OFF_UZ     + SZ_UZ;      // delta=0 -> zero init
constexpr size_t OFF_END    = OFF_UI8    + SZ_UI8;

extern "C" void kernel_launch(void* const* d_in, const int* in_sizes, int n_in,
                              void* d_out, int out_size, void* d_ws, size_t ws_size,
                              hipStream_t stream) {
  const float* x      = (const float*)d_in[0];
  const float* noise  = (const float*)d_in[1];
  const float* Wihmu  = (const float*)d_in[2];
  const float* Whhmu  = (const float*)d_in[3];
  const float* bmu    = (const float*)d_in[4];
  const float* Wihlv  = (const float*)d_in[5];
  const float* Whhlv  = (const float*)d_in[6];
  const float* blv    = (const float*)d_in[7];
  const float* Wmufc  = (const float*)d_in[8];
  const float* bmufc  = (const float*)d_in[9];
  const float* Wlvfc  = (const float*)d_in[10];
  const float* blvfc  = (const float*)d_in[11];
  const float* Wihdec = (const float*)d_in[12];
  const float* Whhdec = (const float*)d_in[13];
  const float* bdec   = (const float*)d_in[14];
  const float* Wwrite = (const float*)d_in[15];
  const float* bwrite = (const float*)d_in[16];
  int T = in_sizes[1] / (B_SZ*NZ);

  if (ws_size < OFF_END) return;

  char* ws = (char*)d_ws;
  unsigned short* wab   = (unsigned short*)(ws + OFF_WAB);
  unsigned char*  wi8   = (unsigned char*)(ws + OFF_WI8);
  unsigned short* whc   = (unsigned short*)(ws + OFF_WHC);
  unsigned short* whh   = (unsigned short*)(ws + OFF_WHH);
  unsigned short* wdec  = (unsigned short*)(ws + OFF_WDEC);
  unsigned short* wwr   = (unsigned short*)(ws + OFF_WWR);
  unsigned short* wfcmu = (unsigned short*)(ws + OFF_WFCMU);
  unsigned short* wfclv = (unsigned short*)(ws + OFF_WFCLV);
  unsigned short* xbf   = (unsigned short*)(ws + OFF_XBF);
  float* csPart = (float*)(ws + OFF_CSPART);
  float* colsum = (float*)(ws + OFF_CSUM);
  float* g0     = (float*)(ws + OFF_G0);
  float* gpart  = (float*)(ws + OFF_GPART);
  float* gdecH  = (float*)(ws + OFF_GDECH);
  float* canvas = (float*)(ws + OFF_CANVAS);
  float* cmu    = (float*)(ws + OFF_CMU);
  float* clv    = (float*)(ws + OFF_CLV);
  float* cdec   = (float*)(ws + OFF_CDEC);
  unsigned short* hmup = (unsigned short*)(ws + OFF_HMUP);
  unsigned short* hlvp = (unsigned short*)(ws + OFF_HLVP);
  unsigned short* uhd  = (unsigned short*)(ws + OFF_UHD);
  unsigned short* uz   = (unsigned short*)(ws + OFF_UZ);
  signed char* ui8 = (signed char*)(ws + OFF_UI8);

  float* out = (float*)d_out;
  float* outMu = out + (size_t)B_SZ*IMGSZ;
  float* outLv = outMu + (size_t)T*B_SZ*NZ;

  dim3 blk(256);

  k_pack_all<<<R_MISC, blk, 0, stream>>>(Wihmu, Wihlv, Whhmu, Whhlv,
                                         Whhdec, Wihdec, Wwrite, Wmufc, Wlvfc, x,
                                         wab, wi8, csPart, whc, whh, wdec, wwr,
                                         wfcmu, wfclv, xbf);
  k_csred<<<(NENC + 255)/256, blk, 0, stream>>>(csPart, colsum);
  hipMemsetAsync(ws + OFF_CANVAS, 0, OFF_END - OFF_CANVAS, stream);

  k_g0<<<800, blk, 0, stream>>>(xbf, wab, gpart);
  k_g0red<<<GSZ/256, blk, 0, stream>>>(gpart, g0);

  for (int t = 0; t < T; ++t){
    k_enc<<<600, blk, 0, stream>>>(ui8, (const signed char*)wi8, uhd, whc,
                                   hmup, hlvp, whh, wdec, gpart, gdecH);
    k_cell<<<B_SZ, 512, 0, stream>>>(g0, gpart, colsum, bmu, blv, cmu, clv,
                                     hmup, hlvp, wfcmu, wfclv, bmufc, blvfc,
                                     noise + (size_t)t*B_SZ*NZ,
                                     outMu + (size_t)t*B_SZ*NZ,
                                     outLv + (size_t)t*B_SZ*NZ, uz);
    k_decz<<<100, blk, 0, stream>>>(uz, wdec, gdecH, bdec, cdec, uhd);
    k_write<<<IMGSZ/64, blk, 0, stream>>>(uhd, wwr, bwrite, canvas, ui8);
  }

  k_final<<<(B_SZ*IMGSZ)/256, blk, 0, stream>>>(canvas, out);
}